// Round 7
// baseline (253.126 us; speedup 1.0000x reference)
//
#include <hip/hip_runtime.h>

#define TPB 1024   // one 16384-pt FFT per block, 16 points/thread/phase

// Padded LDS addressing (float2 units): physical = p + 2*(p>>5).
__device__ constexpr int PX(int p) { return p + 2 * (p >> 5); }

#define LDS_F2 17408   // PX(16383)=17405 -> 139,264 B (1 block/CU)
#define LDS_BYTES (LDS_F2 * 8)

#define PIF 3.14159265358979323846f
#define C8 0.92387953251128674f   // cos(pi/8)
#define S8 0.38268343236508978f   // sin(pi/8)

struct Tw { float c1,s1,c2,s2,c3,s3; };

__device__ __forceinline__ Tw tw_make(float c1, float s1) {
  Tw w;
  w.c1 = c1; w.s1 = s1;
  w.c2 = c1*c1 - s1*s1;      w.s2 = 2.f*c1*s1;
  w.c3 = c1*w.c2 - s1*w.s2;  w.s3 = c1*w.s2 + s1*w.c2;
  return w;
}
__device__ __forceinline__ Tw tw_angle(float a) {
  float s, c; __sincosf(a, &s, &c); return tw_make(c, s);
}

// DIF radix-4 (forward): butterfly then twiddles on outputs 1..3.
__device__ __forceinline__ void r4dif(float2&a,float2&b,float2&c,float2&d,const Tw&w){
  float t0r=a.x+c.x, t0i=a.y+c.y, t1r=a.x-c.x, t1i=a.y-c.y;
  float t2r=b.x+d.x, t2i=b.y+d.y, t3r=b.x-d.x, t3i=b.y-d.y;
  float u0r=t0r+t2r, u0i=t0i+t2i, u2r=t0r-t2r, u2i=t0i-t2i;
  float u1r=t1r+t3i, u1i=t1i-t3r, u3r=t1r-t3i, u3i=t1i+t3r;
  a = make_float2(u0r, u0i);
  b = make_float2(u1r*w.c1 - u1i*w.s1, u1r*w.s1 + u1i*w.c1);
  c = make_float2(u2r*w.c2 - u2i*w.s2, u2r*w.s2 + u2i*w.c2);
  d = make_float2(u3r*w.c3 - u3i*w.s3, u3r*w.s3 + u3i*w.c3);
}
// Same with inputs c=d=0 (zero-padded upper half of the signal).
__device__ __forceinline__ void r4dif_z(float2&a,float2&b,float2&c,float2&d,const Tw&w){
  float u0r=a.x+b.x, u0i=a.y+b.y, u2r=a.x-b.x, u2i=a.y-b.y;
  float u1r=a.x+b.y, u1i=a.y-b.x, u3r=a.x-b.y, u3i=a.y+b.x;
  a = make_float2(u0r, u0i);
  b = make_float2(u1r*w.c1 - u1i*w.s1, u1r*w.s1 + u1i*w.c1);
  c = make_float2(u2r*w.c2 - u2i*w.s2, u2r*w.s2 + u2i*w.c2);
  d = make_float2(u3r*w.c3 - u3i*w.s3, u3r*w.s3 + u3i*w.c3);
}
__device__ __forceinline__ void r4dif_nt(float2&a,float2&b,float2&c,float2&d){
  float t0r=a.x+c.x, t0i=a.y+c.y, t1r=a.x-c.x, t1i=a.y-c.y;
  float t2r=b.x+d.x, t2i=b.y+d.y, t3r=b.x-d.x, t3i=b.y-d.y;
  a = make_float2(t0r+t2r, t0i+t2i);
  b = make_float2(t1r+t3i, t1i-t3r);
  c = make_float2(t0r-t2r, t0i-t2i);
  d = make_float2(t1r-t3i, t1i+t3r);
}
// DIT radix-4 (inverse): twiddles (positive angles) on inputs 1..3, then combine.
__device__ __forceinline__ void r4dit(float2&a,float2&b,float2&c,float2&d,const Tw&w){
  float v1r=b.x*w.c1 - b.y*w.s1, v1i=b.x*w.s1 + b.y*w.c1;
  float v2r=c.x*w.c2 - c.y*w.s2, v2i=c.x*w.s2 + c.y*w.c2;
  float v3r=d.x*w.c3 - d.y*w.s3, v3i=d.x*w.s3 + d.y*w.c3;
  float ar=a.x, ai=a.y;
  a = make_float2(ar+v1r+v2r+v3r, ai+v1i+v2i+v3i);
  b = make_float2(ar-v1i-v2r+v3i, ai+v1r-v2i-v3r);
  c = make_float2(ar-v1r+v2r-v3r, ai-v1i+v2i-v3i);
  d = make_float2(ar+v1i-v2r-v3i, ai-v1r-v2i+v3r);
}
__device__ __forceinline__ void r4dit_nt(float2&a,float2&b,float2&c,float2&d){
  float v1r=b.x, v1i=b.y, v2r=c.x, v2i=c.y, v3r=d.x, v3i=d.y;
  float ar=a.x, ai=a.y;
  a = make_float2(ar+v1r+v2r+v3r, ai+v1i+v2i+v3i);
  b = make_float2(ar-v1i-v2r+v3i, ai+v1r-v2i-v3r);
  c = make_float2(ar-v1r+v2r-v3r, ai-v1i+v2i-v3i);
  d = make_float2(ar+v1i-v2r-v3i, ai-v1r-v2i+v3r);
}

// Fused radix-16 = two radix-4 passes in registers.
__device__ __forceinline__ void r16_fwd(float2 (&e)[16], float aA, float aB) {
  float c1, s1; __sincosf(aA, &s1, &c1);
#pragma unroll
  for (int r = 0; r < 4; ++r) {
    if (r) { float t = c1*C8 + s1*S8; s1 = s1*C8 - c1*S8; c1 = t; }  // angle -= pi/8
    Tw w = tw_make(c1, s1);
    r4dif(e[r], e[r+4], e[r+8], e[r+12], w);
  }
  Tw wb = tw_angle(aB);
#pragma unroll
  for (int m = 0; m < 4; ++m) r4dif(e[4*m], e[4*m+1], e[4*m+2], e[4*m+3], wb);
}
__device__ __forceinline__ void r16_fwd_z(float2 (&e)[16], float aA, float aB) {
  float c1, s1; __sincosf(aA, &s1, &c1);
#pragma unroll
  for (int r = 0; r < 4; ++r) {
    if (r) { float t = c1*C8 + s1*S8; s1 = s1*C8 - c1*S8; c1 = t; }
    Tw w = tw_make(c1, s1);
    r4dif_z(e[r], e[r+4], e[r+8], e[r+12], w);
  }
  Tw wb = tw_angle(aB);
#pragma unroll
  for (int m = 0; m < 4; ++m) r4dif(e[4*m], e[4*m+1], e[4*m+2], e[4*m+3], wb);
}
__device__ __forceinline__ void r16_inv(float2 (&e)[16], float aA, float aB) {
  Tw wa = tw_angle(aA);
#pragma unroll
  for (int j = 0; j < 4; ++j) r4dit(e[4*j], e[4*j+1], e[4*j+2], e[4*j+3], wa);
  float c1, s1; __sincosf(aB, &s1, &c1);
#pragma unroll
  for (int q = 0; q < 4; ++q) {
    if (q) { float t = c1*C8 - s1*S8; s1 = s1*C8 + c1*S8; c1 = t; }  // angle += pi/8
    Tw w = tw_make(c1, s1);
    r4dit(e[q], e[q+4], e[q+8], e[q+12], w);
  }
}

// Forward middle phases: radix-16 at stride 64 (stages 256,64), then at
// stride 4 (stages 16,4).
__device__ __forceinline__ void fwd_mid(float2* A, int tid) {
  __syncthreads();
  {
    const int c = tid & 63;
    const int pb = PX(((tid >> 6) << 10) | c);
    float2 e[16];
#pragma unroll
    for (int k = 0; k < 16; ++k) e[k] = A[pb + PX(64*k)];
    r16_fwd(e, (float)c * (-PIF/512.f), (float)c * (-PIF/128.f));
#pragma unroll
    for (int k = 0; k < 16; ++k) A[pb + PX(64*k)] = e[k];
  }
  __syncthreads();
  {
    const int c = tid & 3;
    const int pb = PX(((tid >> 2) << 6) | c);
    float2 e[16];
#pragma unroll
    for (int k = 0; k < 16; ++k) e[k] = A[pb + PX(4*k)];
    r16_fwd(e, (float)c * (-PIF/32.f), (float)c * (-PIF/8.f));
#pragma unroll
    for (int k = 0; k < 16; ++k) A[pb + PX(4*k)] = e[k];
  }
  __syncthreads();
}

// Hhat[f][p] = scrambled FFT16384(h[f] zero-padded) / 16384
__global__ __launch_bounds__(TPB) void h_fft(const float* __restrict__ h,
                                             float2* __restrict__ Hbuf) {
  extern __shared__ __align__(16) float2 A[];
  const int tid = threadIdx.x;
  const int f = blockIdx.x;
  const float* hr = h + (size_t)f * 8192;
  float2 e[16];
#pragma unroll
  for (int k = 0; k < 8; ++k) e[k] = make_float2(hr[tid + 1024*k], 0.f);
  r16_fwd_z(e, (float)tid * (-PIF/8192.f), (float)tid * (-PIF/2048.f));
  const int pt = PX(tid);
#pragma unroll
  for (int k = 0; k < 16; ++k) A[pt + PX(1024*k)] = e[k];
  fwd_mid(A, tid);
  const float sc = 1.f / 16384.f;
  float2* orow = Hbuf + (size_t)f * 16384;
  const int p4 = PX(4*tid);
#pragma unroll
  for (int m = 0; m < 4; ++m) {
    const int pp = p4 + PX(4096*m);
    float4 lo = *(const float4*)&A[pp];
    float4 hi = *(const float4*)&A[pp+2];
    float2 a = make_float2(lo.x, lo.y), b = make_float2(lo.z, lo.w);
    float2 c = make_float2(hi.x, hi.y), d = make_float2(hi.z, hi.w);
    r4dif_nt(a, b, c, d);
    const int p = 4*tid + 4096*m;
    *(float4*)&orow[p]   = make_float4(a.x*sc, a.y*sc, b.x*sc, b.y*sc);
    *(float4*)&orow[p+2] = make_float4(c.x*sc, c.y*sc, d.x*sc, d.y*sc);
  }
}

// u (8,8192,256) -> xT (2048,8192).
// LDS tile float[64][65]: stride 65 == 1 (mod 32) makes both the scalar
// write phase and the scalar read phase exactly 2 lanes/bank (free).
__global__ __launch_bounds__(256) void transpose_in(const float* __restrict__ u,
                                                    float* __restrict__ xT) {
  __shared__ float T[64][65];
  const int l0 = blockIdx.x * 64, d0 = blockIdx.y * 64, b = blockIdx.z;
  const int t = threadIdx.x, c = t & 15, r = t >> 4;
  const float4* u4 = (const float4*)(u + (size_t)b * 8192 * 256);
#pragma unroll
  for (int p = 0; p < 4; ++p) {
    int li = r + 16 * p;
    float4 v = u4[(size_t)(l0 + li) * 64 + (d0 >> 2) + c];
    T[4*c+0][li] = v.x; T[4*c+1][li] = v.y; T[4*c+2][li] = v.z; T[4*c+3][li] = v.w;
  }
  __syncthreads();
#pragma unroll
  for (int p = 0; p < 4; ++p) {
    int dr = r + 16 * p;
    float4 w = make_float4(T[dr][4*c+0], T[dr][4*c+1], T[dr][4*c+2], T[dr][4*c+3]);
    *(float4*)&xT[(size_t)(b * 256 + d0 + dr) * 8192 + l0 + 4 * c] = w;
  }
}

// yT (2048,8192) -> out (8,8192,256), same padded-tile structure.
__global__ __launch_bounds__(256) void transpose_out(const float* __restrict__ yT,
                                                     float* __restrict__ out) {
  __shared__ float T[64][65];   // [l_local][d_local]
  const int l0 = blockIdx.x * 64, d0 = blockIdx.y * 64, b = blockIdx.z;
  const int t = threadIdx.x, c = t & 15, r = t >> 4;
#pragma unroll
  for (int p = 0; p < 4; ++p) {
    int di = r + 16 * p;
    float4 v = *(const float4*)&yT[(size_t)(b * 256 + d0 + di) * 8192 + l0 + 4 * c];
    T[4*c+0][di] = v.x; T[4*c+1][di] = v.y; T[4*c+2][di] = v.z; T[4*c+3][di] = v.w;
  }
  __syncthreads();
#pragma unroll
  for (int p = 0; p < 4; ++p) {
    int lr = r + 16 * p;
    float4 w = make_float4(T[lr][4*c+0], T[lr][4*c+1], T[lr][4*c+2], T[lr][4*c+3]);
    *(float4*)&out[(size_t)(b * 8192 + l0 + lr) * 256 + d0 + 4 * c] = w;
  }
}

// One block per ROW PAIR (r, r+1 share filter f = r>>3).
// Hhat prefetch v3: loads issued after phase0's LDS write, then an
// operand-free `asm volatile("" ::: "memory")`. The clobber (a) forbids
// sinking the loads below it (the asm may write the memory they read --
// unlike __syncthreads, which read-only loads may legally cross under the
// DRF assumption; that's how v1/v2 degenerated to loads-at-use), and
// (b) forbids rematerializing the values after it (memory may have
// changed), so the 32 VGPRs stay live. No vmcnt wait is forced at the
// clobber -- waits land before first use (PW phase), so the loads drain
// under fwd_mid's compute. VGPR cap 128 via __launch_bounds__(TPB, 4)
// (occupancy is LDS-forced to 1 block/CU = 4 waves/EU anyway).
__global__ __launch_bounds__(TPB, 4) void conv_main(const float* __restrict__ xT,
                                                    const float2* __restrict__ Hbuf,
                                                    float* yT) {
  extern __shared__ __align__(16) float2 A[];
  const int tid = threadIdx.x;
  // XCD swizzle: the 4 pair-blocks of one filter land on the same XCD.
  const int i = blockIdx.x;
  const int f = ((i >> 5) << 3) | (i & 7);        // filter 0..255
  const int r = (f << 3) | (((i >> 3) & 3) << 1); // row 0..2046 (even)
  const float* x0 = xT + (size_t)r * 8192;
  const float* x1 = xT + (size_t)(r + 1) * 8192;

  // ---- fwd phase 0 (stages 4096,1024) straight from global, zero-pad free ----
  float2 e[16];
#pragma unroll
  for (int k = 0; k < 8; ++k)
    e[k] = make_float2(x0[tid + 1024*k], x1[tid + 1024*k]);
  r16_fwd_z(e, (float)tid * (-PIF/8192.f), (float)tid * (-PIF/2048.f));
  const int pt = PX(tid);
#pragma unroll
  for (int k = 0; k < 16; ++k) A[pt + PX(1024*k)] = e[k];

  // ---- Hhat prefetch: issue now; clobber pins issue point & liveness ----
  const float2* Hrow = Hbuf + (size_t)f * 16384;
  float4 hpre[8];
#pragma unroll
  for (int m = 0; m < 4; ++m) {
    hpre[2*m]   = *(const float4*)&Hrow[4*tid + 4096*m];
    hpre[2*m+1] = *(const float4*)&Hrow[4*tid + 4096*m + 2];
  }
  asm volatile("" ::: "memory");

  fwd_mid(A, tid);

  // ---- fused: fwd stride-1 radix-4 -> xHhat -> inv stride-1 radix-4 ----
  {
    const int p4 = PX(4*tid);
#pragma unroll
    for (int m = 0; m < 4; ++m) {
      const int pp = p4 + PX(4096*m);
      float4 lo = *(const float4*)&A[pp];
      float4 hi = *(const float4*)&A[pp+2];
      float2 a = make_float2(lo.x, lo.y), b = make_float2(lo.z, lo.w);
      float2 c = make_float2(hi.x, hi.y), d = make_float2(hi.z, hi.w);
      r4dif_nt(a, b, c, d);
      float4 h0 = hpre[2*m];
      float4 h1 = hpre[2*m+1];
      float2 an = make_float2(a.x*h0.x - a.y*h0.y, a.x*h0.y + a.y*h0.x);
      float2 bn = make_float2(b.x*h0.z - b.y*h0.w, b.x*h0.w + b.y*h0.z);
      float2 cn = make_float2(c.x*h1.x - c.y*h1.y, c.x*h1.y + c.y*h1.x);
      float2 dn = make_float2(d.x*h1.z - d.y*h1.w, d.x*h1.w + d.y*h1.z);
      r4dit_nt(an, bn, cn, dn);
      *(float4*)&A[pp]   = make_float4(an.x, an.y, bn.x, bn.y);
      *(float4*)&A[pp+2] = make_float4(cn.x, cn.y, dn.x, dn.y);
    }
  }
  __syncthreads();

  // ---- inv phase (stages 4,16), stride 4 ----
  {
    const int c = tid & 3;
    const int pb = PX(((tid >> 2) << 6) | c);
#pragma unroll
    for (int k = 0; k < 16; ++k) e[k] = A[pb + PX(4*k)];
    r16_inv(e, (float)c * (PIF/8.f), (float)c * (PIF/32.f));
#pragma unroll
    for (int k = 0; k < 16; ++k) A[pb + PX(4*k)] = e[k];
  }
  __syncthreads();

  // ---- inv phase (stages 64,256), stride 64 ----
  {
    const int c = tid & 63;
    const int pb = PX(((tid >> 6) << 10) | c);
#pragma unroll
    for (int k = 0; k < 16; ++k) e[k] = A[pb + PX(64*k)];
    r16_inv(e, (float)c * (PIF/128.f), (float)c * (PIF/512.f));
#pragma unroll
    for (int k = 0; k < 16; ++k) A[pb + PX(64*k)] = e[k];
  }
  __syncthreads();

  // ---- inv phase (stages 1024,4096), stride 1024; y window direct to global ----
  {
#pragma unroll
    for (int k = 0; k < 16; ++k) e[k] = A[pt + PX(1024*k)];
    r16_inv(e, (float)tid * (PIF/2048.f), (float)tid * (PIF/8192.f));
    float* y0 = yT + (size_t)r * 8192;
    float* y1 = yT + (size_t)(r + 1) * 8192;
#pragma unroll
    for (int k = 4; k <= 10; ++k) {
      const int l = tid + 1024*k - 4095;
      y0[l] = e[k].x; y1[l] = e[k].y;
    }
    if (tid < 1023) { const int l = tid + 1024*11 - 4095; y0[l] = e[11].x; y1[l] = e[11].y; }
    else            { y0[0] = e[3].x;  y1[0] = e[3].y; }   // idx 4095 from k=3
  }
}

extern "C" void kernel_launch(void* const* d_in, const int* in_sizes, int n_in,
                              void* d_out, int out_size, void* d_ws, size_t ws_size,
                              hipStream_t stream) {
  (void)in_sizes; (void)n_in; (void)out_size; (void)ws_size;
  const float* u = (const float*)d_in[0];   // (8, 8192, 256) f32
  const float* h = (const float*)d_in[1];   // (256, 8192) f32
  float* out = (float*)d_out;               // (8, 8192, 256) f32
  // workspace: [xT/yT: 2048*8192 f32 = 64 MB][Hhat: 256*16384 float2 = 32 MB]
  float* xT = (float*)d_ws;
  float2* Hbuf = (float2*)((char*)d_ws + (size_t)2048 * 8192 * 4);

  static_assert(LDS_BYTES == 139264, "lds");
  (void)hipFuncSetAttribute((const void*)h_fft,
      hipFuncAttributeMaxDynamicSharedMemorySize, LDS_BYTES);
  (void)hipFuncSetAttribute((const void*)conv_main,
      hipFuncAttributeMaxDynamicSharedMemorySize, LDS_BYTES);

  h_fft<<<256, TPB, LDS_BYTES, stream>>>(h, Hbuf);
  transpose_in<<<dim3(128, 4, 8), 256, 0, stream>>>(u, xT);
  conv_main<<<1024, TPB, LDS_BYTES, stream>>>(xT, Hbuf, xT);  // yT aliases xT
  transpose_out<<<dim3(128, 4, 8), 256, 0, stream>>>(xT, out);
}

// Round 8
// 240.853 us; speedup vs baseline: 1.0510x; 1.0510x over previous
//
#include <hip/hip_runtime.h>

#define TPB 1024   // one 16384-pt FFT per block, 16 points/thread/phase

// Padded LDS addressing (float2 units): physical = p + 2*(p>>5).
__device__ constexpr int PX(int p) { return p + 2 * (p >> 5); }

#define LDS_F2 17408   // PX(16383)=17405 -> 139,264 B (1 block/CU)
#define LDS_BYTES (LDS_F2 * 8)

#define PIF 3.14159265358979323846f
#define C8 0.92387953251128674f   // cos(pi/8)
#define S8 0.38268343236508978f   // sin(pi/8)

struct Tw { float c1,s1,c2,s2,c3,s3; };

__device__ __forceinline__ Tw tw_make(float c1, float s1) {
  Tw w;
  w.c1 = c1; w.s1 = s1;
  w.c2 = c1*c1 - s1*s1;      w.s2 = 2.f*c1*s1;
  w.c3 = c1*w.c2 - s1*w.s2;  w.s3 = c1*w.s2 + s1*w.c2;
  return w;
}
__device__ __forceinline__ Tw tw_angle(float a) {
  float s, c; __sincosf(a, &s, &c); return tw_make(c, s);
}

// DIF radix-4 (forward): butterfly then twiddles on outputs 1..3.
__device__ __forceinline__ void r4dif(float2&a,float2&b,float2&c,float2&d,const Tw&w){
  float t0r=a.x+c.x, t0i=a.y+c.y, t1r=a.x-c.x, t1i=a.y-c.y;
  float t2r=b.x+d.x, t2i=b.y+d.y, t3r=b.x-d.x, t3i=b.y-d.y;
  float u0r=t0r+t2r, u0i=t0i+t2i, u2r=t0r-t2r, u2i=t0i-t2i;
  float u1r=t1r+t3i, u1i=t1i-t3r, u3r=t1r-t3i, u3i=t1i+t3r;
  a = make_float2(u0r, u0i);
  b = make_float2(u1r*w.c1 - u1i*w.s1, u1r*w.s1 + u1i*w.c1);
  c = make_float2(u2r*w.c2 - u2i*w.s2, u2r*w.s2 + u2i*w.c2);
  d = make_float2(u3r*w.c3 - u3i*w.s3, u3r*w.s3 + u3i*w.c3);
}
// Same with inputs c=d=0 (zero-padded upper half of the signal).
__device__ __forceinline__ void r4dif_z(float2&a,float2&b,float2&c,float2&d,const Tw&w){
  float u0r=a.x+b.x, u0i=a.y+b.y, u2r=a.x-b.x, u2i=a.y-b.y;
  float u1r=a.x+b.y, u1i=a.y-b.x, u3r=a.x-b.y, u3i=a.y+b.x;
  a = make_float2(u0r, u0i);
  b = make_float2(u1r*w.c1 - u1i*w.s1, u1r*w.s1 + u1i*w.c1);
  c = make_float2(u2r*w.c2 - u2i*w.s2, u2r*w.s2 + u2i*w.c2);
  d = make_float2(u3r*w.c3 - u3i*w.s3, u3r*w.s3 + u3i*w.c3);
}
__device__ __forceinline__ void r4dif_nt(float2&a,float2&b,float2&c,float2&d){
  float t0r=a.x+c.x, t0i=a.y+c.y, t1r=a.x-c.x, t1i=a.y-c.y;
  float t2r=b.x+d.x, t2i=b.y+d.y, t3r=b.x-d.x, t3i=b.y-d.y;
  a = make_float2(t0r+t2r, t0i+t2i);
  b = make_float2(t1r+t3i, t1i-t3r);
  c = make_float2(t0r-t2r, t0i-t2i);
  d = make_float2(t1r-t3i, t1i+t3r);
}
// DIT radix-4 (inverse): twiddles (positive angles) on inputs 1..3, then combine.
__device__ __forceinline__ void r4dit(float2&a,float2&b,float2&c,float2&d,const Tw&w){
  float v1r=b.x*w.c1 - b.y*w.s1, v1i=b.x*w.s1 + b.y*w.c1;
  float v2r=c.x*w.c2 - c.y*w.s2, v2i=c.x*w.s2 + c.y*w.c2;
  float v3r=d.x*w.c3 - d.y*w.s3, v3i=d.x*w.s3 + d.y*w.c3;
  float ar=a.x, ai=a.y;
  a = make_float2(ar+v1r+v2r+v3r, ai+v1i+v2i+v3i);
  b = make_float2(ar-v1i-v2r+v3i, ai+v1r-v2i-v3r);
  c = make_float2(ar-v1r+v2r-v3r, ai-v1i+v2i-v3i);
  d = make_float2(ar+v1i-v2r-v3i, ai-v1r-v2i+v3r);
}
__device__ __forceinline__ void r4dit_nt(float2&a,float2&b,float2&c,float2&d){
  float v1r=b.x, v1i=b.y, v2r=c.x, v2i=c.y, v3r=d.x, v3i=d.y;
  float ar=a.x, ai=a.y;
  a = make_float2(ar+v1r+v2r+v3r, ai+v1i+v2i+v3i);
  b = make_float2(ar-v1i-v2r+v3i, ai+v1r-v2i-v3r);
  c = make_float2(ar-v1r+v2r-v3r, ai-v1i+v2i-v3i);
  d = make_float2(ar+v1i-v2r-v3i, ai-v1r-v2i+v3r);
}

// Fused radix-16 = two radix-4 passes in registers.
__device__ __forceinline__ void r16_fwd(float2 (&e)[16], float aA, float aB) {
  float c1, s1; __sincosf(aA, &s1, &c1);
#pragma unroll
  for (int r = 0; r < 4; ++r) {
    if (r) { float t = c1*C8 + s1*S8; s1 = s1*C8 - c1*S8; c1 = t; }  // angle -= pi/8
    Tw w = tw_make(c1, s1);
    r4dif(e[r], e[r+4], e[r+8], e[r+12], w);
  }
  Tw wb = tw_angle(aB);
#pragma unroll
  for (int m = 0; m < 4; ++m) r4dif(e[4*m], e[4*m+1], e[4*m+2], e[4*m+3], wb);
}
__device__ __forceinline__ void r16_fwd_z(float2 (&e)[16], float aA, float aB) {
  float c1, s1; __sincosf(aA, &s1, &c1);
#pragma unroll
  for (int r = 0; r < 4; ++r) {
    if (r) { float t = c1*C8 + s1*S8; s1 = s1*C8 - c1*S8; c1 = t; }
    Tw w = tw_make(c1, s1);
    r4dif_z(e[r], e[r+4], e[r+8], e[r+12], w);
  }
  Tw wb = tw_angle(aB);
#pragma unroll
  for (int m = 0; m < 4; ++m) r4dif(e[4*m], e[4*m+1], e[4*m+2], e[4*m+3], wb);
}
__device__ __forceinline__ void r16_inv(float2 (&e)[16], float aA, float aB) {
  Tw wa = tw_angle(aA);
#pragma unroll
  for (int j = 0; j < 4; ++j) r4dit(e[4*j], e[4*j+1], e[4*j+2], e[4*j+3], wa);
  float c1, s1; __sincosf(aB, &s1, &c1);
#pragma unroll
  for (int q = 0; q < 4; ++q) {
    if (q) { float t = c1*C8 - s1*S8; s1 = s1*C8 + c1*S8; c1 = t; }  // angle += pi/8
    Tw w = tw_make(c1, s1);
    r4dit(e[q], e[q+4], e[q+8], e[q+12], w);
  }
}

// Forward middle phases: radix-16 at stride 64 (stages 256,64), then at
// stride 4 (stages 16,4).
__device__ __forceinline__ void fwd_mid(float2* A, int tid) {
  __syncthreads();
  {
    const int c = tid & 63;
    const int pb = PX(((tid >> 6) << 10) | c);
    float2 e[16];
#pragma unroll
    for (int k = 0; k < 16; ++k) e[k] = A[pb + PX(64*k)];
    r16_fwd(e, (float)c * (-PIF/512.f), (float)c * (-PIF/128.f));
#pragma unroll
    for (int k = 0; k < 16; ++k) A[pb + PX(64*k)] = e[k];
  }
  __syncthreads();
  {
    const int c = tid & 3;
    const int pb = PX(((tid >> 2) << 6) | c);
    float2 e[16];
#pragma unroll
    for (int k = 0; k < 16; ++k) e[k] = A[pb + PX(4*k)];
    r16_fwd(e, (float)c * (-PIF/32.f), (float)c * (-PIF/8.f));
#pragma unroll
    for (int k = 0; k < 16; ++k) A[pb + PX(4*k)] = e[k];
  }
  __syncthreads();
}

// Hhat[f][p] = scrambled FFT16384(h[f] zero-padded) / 16384
__global__ __launch_bounds__(TPB) void h_fft(const float* __restrict__ h,
                                             float2* __restrict__ Hbuf) {
  extern __shared__ __align__(16) float2 A[];
  const int tid = threadIdx.x;
  const int f = blockIdx.x;
  const float* hr = h + (size_t)f * 8192;
  float2 e[16];
#pragma unroll
  for (int k = 0; k < 8; ++k) e[k] = make_float2(hr[tid + 1024*k], 0.f);
  r16_fwd_z(e, (float)tid * (-PIF/8192.f), (float)tid * (-PIF/2048.f));
  const int pt = PX(tid);
#pragma unroll
  for (int k = 0; k < 16; ++k) A[pt + PX(1024*k)] = e[k];
  fwd_mid(A, tid);
  const float sc = 1.f / 16384.f;
  float2* orow = Hbuf + (size_t)f * 16384;
  const int p4 = PX(4*tid);
#pragma unroll
  for (int m = 0; m < 4; ++m) {
    const int pp = p4 + PX(4096*m);
    float4 lo = *(const float4*)&A[pp];
    float4 hi = *(const float4*)&A[pp+2];
    float2 a = make_float2(lo.x, lo.y), b = make_float2(lo.z, lo.w);
    float2 c = make_float2(hi.x, hi.y), d = make_float2(hi.z, hi.w);
    r4dif_nt(a, b, c, d);
    const int p = 4*tid + 4096*m;
    *(float4*)&orow[p]   = make_float4(a.x*sc, a.y*sc, b.x*sc, b.y*sc);
    *(float4*)&orow[p+2] = make_float4(c.x*sc, c.y*sc, d.x*sc, d.y*sc);
  }
}

// u (8,8192,256) -> xT (2048,8192).
// LDS tile float[64][65]: stride 65 == 1 (mod 32) makes both the scalar
// write phase and the scalar read phase exactly 2 lanes/bank (free).
__global__ __launch_bounds__(256) void transpose_in(const float* __restrict__ u,
                                                    float* __restrict__ xT) {
  __shared__ float T[64][65];
  const int l0 = blockIdx.x * 64, d0 = blockIdx.y * 64, b = blockIdx.z;
  const int t = threadIdx.x, c = t & 15, r = t >> 4;
  const float4* u4 = (const float4*)(u + (size_t)b * 8192 * 256);
#pragma unroll
  for (int p = 0; p < 4; ++p) {
    int li = r + 16 * p;
    float4 v = u4[(size_t)(l0 + li) * 64 + (d0 >> 2) + c];
    T[4*c+0][li] = v.x; T[4*c+1][li] = v.y; T[4*c+2][li] = v.z; T[4*c+3][li] = v.w;
  }
  __syncthreads();
#pragma unroll
  for (int p = 0; p < 4; ++p) {
    int dr = r + 16 * p;
    float4 w = make_float4(T[dr][4*c+0], T[dr][4*c+1], T[dr][4*c+2], T[dr][4*c+3]);
    *(float4*)&xT[(size_t)(b * 256 + d0 + dr) * 8192 + l0 + 4 * c] = w;
  }
}

// yT (2048,8192) -> out (8,8192,256), same padded-tile structure.
__global__ __launch_bounds__(256) void transpose_out(const float* __restrict__ yT,
                                                     float* __restrict__ out) {
  __shared__ float T[64][65];   // [l_local][d_local]
  const int l0 = blockIdx.x * 64, d0 = blockIdx.y * 64, b = blockIdx.z;
  const int t = threadIdx.x, c = t & 15, r = t >> 4;
#pragma unroll
  for (int p = 0; p < 4; ++p) {
    int di = r + 16 * p;
    float4 v = *(const float4*)&yT[(size_t)(b * 256 + d0 + di) * 8192 + l0 + 4 * c];
    T[4*c+0][di] = v.x; T[4*c+1][di] = v.y; T[4*c+2][di] = v.z; T[4*c+3][di] = v.w;
  }
  __syncthreads();
#pragma unroll
  for (int p = 0; p < 4; ++p) {
    int lr = r + 16 * p;
    float4 w = make_float4(T[lr][4*c+0], T[lr][4*c+1], T[lr][4*c+2], T[lr][4*c+3]);
    *(float4*)&out[(size_t)(b * 8192 + l0 + lr) * 256 + d0 + 4 * c] = w;
  }
}

// One block per ROW PAIR (r, r+1 share filter f = r>>3).
// R1-exact structure (best verified: conv=96.6us). Register prefetch of Hhat
// was tried 3 ways (R2/R5/R7): the allocator refuses to keep 32 VGPRs live
// across fwd_mid (sinks loads to use / spills), each attempt cost +4.7us.
// Hhat loads therefore live inside the PW phase, hoisted above the LDS
// reads to give the scheduler maximal within-phase freedom.
__global__ __launch_bounds__(TPB) void conv_main(const float* __restrict__ xT,
                                                 const float2* __restrict__ Hbuf,
                                                 float* yT) {
  extern __shared__ __align__(16) float2 A[];
  const int tid = threadIdx.x;
  // XCD swizzle: the 4 pair-blocks of one filter land on the same XCD.
  const int i = blockIdx.x;
  const int f = ((i >> 5) << 3) | (i & 7);        // filter 0..255
  const int r = (f << 3) | (((i >> 3) & 3) << 1); // row 0..2046 (even)
  const float* x0 = xT + (size_t)r * 8192;
  const float* x1 = xT + (size_t)(r + 1) * 8192;

  // ---- fwd phase 0 (stages 4096,1024) straight from global, zero-pad free ----
  float2 e[16];
#pragma unroll
  for (int k = 0; k < 8; ++k)
    e[k] = make_float2(x0[tid + 1024*k], x1[tid + 1024*k]);
  r16_fwd_z(e, (float)tid * (-PIF/8192.f), (float)tid * (-PIF/2048.f));
  const int pt = PX(tid);
#pragma unroll
  for (int k = 0; k < 16; ++k) A[pt + PX(1024*k)] = e[k];

  fwd_mid(A, tid);

  // ---- fused: fwd stride-1 radix-4 -> xHhat -> inv stride-1 radix-4 ----
  {
    const float2* Hrow = Hbuf + (size_t)f * 16384;
    const int p4 = PX(4*tid);
#pragma unroll
    for (int m = 0; m < 4; ++m) {
      const int pp = p4 + PX(4096*m);
      const int p = 4*tid + 4096*m;
      // Hhat loads first: issue before the LDS reads so HBM/L2 latency
      // overlaps the ds_read + butterfly work of this m-chunk.
      float4 h0 = *(const float4*)&Hrow[p];
      float4 h1 = *(const float4*)&Hrow[p+2];
      float4 lo = *(const float4*)&A[pp];
      float4 hi = *(const float4*)&A[pp+2];
      float2 a = make_float2(lo.x, lo.y), b = make_float2(lo.z, lo.w);
      float2 c = make_float2(hi.x, hi.y), d = make_float2(hi.z, hi.w);
      r4dif_nt(a, b, c, d);
      float2 an = make_float2(a.x*h0.x - a.y*h0.y, a.x*h0.y + a.y*h0.x);
      float2 bn = make_float2(b.x*h0.z - b.y*h0.w, b.x*h0.w + b.y*h0.z);
      float2 cn = make_float2(c.x*h1.x - c.y*h1.y, c.x*h1.y + c.y*h1.x);
      float2 dn = make_float2(d.x*h1.z - d.y*h1.w, d.x*h1.w + d.y*h1.z);
      r4dit_nt(an, bn, cn, dn);
      *(float4*)&A[pp]   = make_float4(an.x, an.y, bn.x, bn.y);
      *(float4*)&A[pp+2] = make_float4(cn.x, cn.y, dn.x, dn.y);
    }
  }
  __syncthreads();

  // ---- inv phase (stages 4,16), stride 4 ----
  {
    const int c = tid & 3;
    const int pb = PX(((tid >> 2) << 6) | c);
#pragma unroll
    for (int k = 0; k < 16; ++k) e[k] = A[pb + PX(4*k)];
    r16_inv(e, (float)c * (PIF/8.f), (float)c * (PIF/32.f));
#pragma unroll
    for (int k = 0; k < 16; ++k) A[pb + PX(4*k)] = e[k];
  }
  __syncthreads();

  // ---- inv phase (stages 64,256), stride 64 ----
  {
    const int c = tid & 63;
    const int pb = PX(((tid >> 6) << 10) | c);
#pragma unroll
    for (int k = 0; k < 16; ++k) e[k] = A[pb + PX(64*k)];
    r16_inv(e, (float)c * (PIF/128.f), (float)c * (PIF/512.f));
#pragma unroll
    for (int k = 0; k < 16; ++k) A[pb + PX(64*k)] = e[k];
  }
  __syncthreads();

  // ---- inv phase (stages 1024,4096), stride 1024; y window direct to global ----
  {
#pragma unroll
    for (int k = 0; k < 16; ++k) e[k] = A[pt + PX(1024*k)];
    r16_inv(e, (float)tid * (PIF/2048.f), (float)tid * (PIF/8192.f));
    float* y0 = yT + (size_t)r * 8192;
    float* y1 = yT + (size_t)(r + 1) * 8192;
#pragma unroll
    for (int k = 4; k <= 10; ++k) {
      const int l = tid + 1024*k - 4095;
      y0[l] = e[k].x; y1[l] = e[k].y;
    }
    if (tid < 1023) { const int l = tid + 1024*11 - 4095; y0[l] = e[11].x; y1[l] = e[11].y; }
    else            { y0[0] = e[3].x;  y1[0] = e[3].y; }   // idx 4095 from k=3
  }
}

extern "C" void kernel_launch(void* const* d_in, const int* in_sizes, int n_in,
                              void* d_out, int out_size, void* d_ws, size_t ws_size,
                              hipStream_t stream) {
  (void)in_sizes; (void)n_in; (void)out_size; (void)ws_size;
  const float* u = (const float*)d_in[0];   // (8, 8192, 256) f32
  const float* h = (const float*)d_in[1];   // (256, 8192) f32
  float* out = (float*)d_out;               // (8, 8192, 256) f32
  // workspace: [xT/yT: 2048*8192 f32 = 64 MB][Hhat: 256*16384 float2 = 32 MB]
  float* xT = (float*)d_ws;
  float2* Hbuf = (float2*)((char*)d_ws + (size_t)2048 * 8192 * 4);

  static_assert(LDS_BYTES == 139264, "lds");
  (void)hipFuncSetAttribute((const void*)h_fft,
      hipFuncAttributeMaxDynamicSharedMemorySize, LDS_BYTES);
  (void)hipFuncSetAttribute((const void*)conv_main,
      hipFuncAttributeMaxDynamicSharedMemorySize, LDS_BYTES);

  h_fft<<<256, TPB, LDS_BYTES, stream>>>(h, Hbuf);
  transpose_in<<<dim3(128, 4, 8), 256, 0, stream>>>(u, xT);
  conv_main<<<1024, TPB, LDS_BYTES, stream>>>(xT, Hbuf, xT);  // yT aliases xT
  transpose_out<<<dim3(128, 4, 8), 256, 0, stream>>>(xT, out);
}